// Round 7
// baseline (378.669 us; speedup 1.0000x reference)
//
#include <hip/hip_runtime.h>
#include <hip/hip_bf16.h>

typedef __bf16 bf16x8 __attribute__((ext_vector_type(8)));
typedef float f32x4 __attribute__((ext_vector_type(4)));
typedef short short8 __attribute__((ext_vector_type(8)));
typedef short short4v __attribute__((ext_vector_type(4)));

#define NB 4
#define CC 256
#define SS 4096
#define EE 256

static constexpr float QSCALE = 1.4426950408889634f / 16.0f;  // log2(e)/sqrt(E)

// workspace offsets (bytes)
#define QOFF 0u
#define KOFF 8388608u
#define VOFF 16777216u
#define WOFF 25165824u
#define BOFF 25559040u
#define PAOFF 25690112u   // partial acc f32 [slot][256 o][256 s], then stats float2 [slot][256 s]

#define GLOAD_LDS16(gsrc, ldst) \
    __builtin_amdgcn_global_load_lds((const __attribute__((address_space(1))) void*)(gsrc), \
                                     (__attribute__((address_space(3))) void*)(ldst), 16, 0, 0)

// ---------------- weight prep: fp32 -> bf16 (q rows pre-scaled) ----------------
__global__ __launch_bounds__(256) void prep_kernel(const float* __restrict__ Wq,
                                                   const float* __restrict__ bq,
                                                   const float* __restrict__ Wkv,
                                                   const float* __restrict__ bkv,
                                                   __bf16* __restrict__ wc,
                                                   float* __restrict__ bias) {
    int r = blockIdx.x;
    int t = threadIdx.x;
    float v;
    if (r < 256) v = Wq[r * 256 + t] * QSCALE;
    else         v = Wkv[(r - 256) * 256 + t];
    wc[r * 256 + t] = (__bf16)v;
    if (t == 0) bias[r] = (r < 256) ? bq[r] * QSCALE : bkv[r - 256];
}

// ---------------- projection: q,k [n][S][E] bf16 ; v transposed [n][O][S] bf16 ----------------
__global__ __launch_bounds__(256) void proj_kernel(const float* __restrict__ x,
                                                   const __bf16* __restrict__ wc,
                                                   const float* __restrict__ bias,
                                                   __bf16* __restrict__ qo,
                                                   __bf16* __restrict__ ko,
                                                   __bf16* __restrict__ vo) {
    __shared__ __align__(16) char Ab[32768];
    __shared__ __align__(16) char Wb[32768];
    const int t = threadIdx.x;
    const int lane = t & 63;
    const int w = t >> 6;
    const int n = blockIdx.x >> 6;
    const int s0 = (blockIdx.x & 63) << 6;

    {
        const int sl = t & 15;
        const int cc0 = t >> 4;
        #pragma unroll
        for (int it = 0; it < 2; ++it) {
            int c0 = (cc0 + (it << 4)) << 3;
            float f[8][4];
            #pragma unroll
            for (int r = 0; r < 8; ++r) {
                const float* xp = x + ((long)(n * CC + c0 + r)) * SS + s0 + sl;
                #pragma unroll
                for (int i = 0; i < 4; ++i) f[r][i] = xp[i << 4];
            }
            #pragma unroll
            for (int i = 0; i < 4; ++i) {
                bf16x8 v;
                #pragma unroll
                for (int r = 0; r < 8; ++r) v[r] = (__bf16)f[r][i];
                int srow = sl + (i << 4);
                *(bf16x8*)(Ab + srow * 512 + ((c0 * 2) ^ ((srow & 7) << 4))) = v;
            }
        }
    }
    __syncthreads();

    bf16x8 af[8];
    {
        int arow = (w << 4) + (lane & 15);
        #pragma unroll
        for (int kf = 0; kf < 8; ++kf) {
            int c = ((lane >> 4) << 3) + (kf << 5);
            af[kf] = *(const bf16x8*)(Ab + arow * 512 + ((c * 2) ^ ((arow & 7) << 4)));
        }
    }

    for (int ot = 0; ot < 12; ++ot) {
        #pragma unroll
        for (int p = 0; p < 16; ++p) {
            int row = w + (p << 2);
            int c = lane << 2;
            short4v vv = *(const short4v*)((const short*)wc + (ot * 64 + row) * 256 + c);
            *(short4v*)(Wb + row * 512 + ((c * 2) ^ ((row & 7) << 4))) = vv;
        }
        __syncthreads();

        f32x4 acc[4];
        #pragma unroll
        for (int cb = 0; cb < 4; ++cb) acc[cb] = (f32x4){0.f, 0.f, 0.f, 0.f};
        #pragma unroll
        for (int cb = 0; cb < 4; ++cb) {
            int row = (cb << 4) + (lane & 15);
            #pragma unroll
            for (int kf = 0; kf < 8; ++kf) {
                int c = ((lane >> 4) << 3) + (kf << 5);
                bf16x8 bfr = *(const bf16x8*)(Wb + row * 512 + ((c * 2) ^ ((row & 7) << 4)));
                acc[cb] = __builtin_amdgcn_mfma_f32_16x16x32_bf16(af[kf], bfr, acc[cb], 0, 0, 0);
            }
        }
        __syncthreads();

        __bf16* T = (__bf16*)Wb;
        float bsv[4];
        #pragma unroll
        for (int cb = 0; cb < 4; ++cb) bsv[cb] = bias[ot * 64 + (cb << 4) + (lane & 15)];

        if (ot < 8) {
            #pragma unroll
            for (int cb = 0; cb < 4; ++cb) {
                #pragma unroll
                for (int jj = 0; jj < 4; ++jj) {
                    int srow = (w << 4) + ((lane >> 4) << 2) + jj;
                    T[srow * 72 + (cb << 4) + (lane & 15)] = (__bf16)(acc[cb][jj] + bsv[cb]);
                }
            }
            __syncthreads();
            int s = t >> 2;
            int o0 = (t & 3) << 4;
            short8 r0 = *(const short8*)((const short*)T + s * 72 + o0);
            short8 r1 = *(const short8*)((const short*)T + s * 72 + o0 + 8);
            __bf16* dst = (ot < 4) ? qo : ko;
            long idx = ((long)(n * SS + s0 + s)) * EE + ((ot & 3) << 6) + o0;
            *(short8*)((short*)dst + idx) = r0;
            *(short8*)((short*)dst + idx + 8) = r1;
        } else {
            #pragma unroll
            for (int cb = 0; cb < 4; ++cb) {
                #pragma unroll
                for (int jj = 0; jj < 4; ++jj) {
                    int srow = (w << 4) + ((lane >> 4) << 2) + jj;
                    T[((cb << 4) + (lane & 15)) * 72 + srow] = (__bf16)(acc[cb][jj] + bsv[cb]);
                }
            }
            __syncthreads();
            int o = t >> 2;
            int sc0 = (t & 3) << 4;
            short8 r0 = *(const short8*)((const short*)T + o * 72 + sc0);
            short8 r1 = *(const short8*)((const short*)T + o * 72 + sc0 + 8);
            long idx = ((long)((n << 8) + ((ot - 8) << 6) + o)) * SS + s0 + sc0;
            *(short8*)((short*)vo + idx) = r0;
            *(short8*)((short*)vo + idx + 8) = r1;
        }
        __syncthreads();
    }
}

// ---------------- causal flash attention: QBLK=256 (8 waves x 32q), KVBLK=64 ----------------
// LDS: K[64][256] (32KB, restaged mid-tile) | V^T[2][256][64] dbuf (64KB) | P[8][32][64] swz (32KB)
__global__ __launch_bounds__(512, 2) void attn_kernel(const __bf16* __restrict__ qg,
                                                      const __bf16* __restrict__ kg,
                                                      const __bf16* __restrict__ vg,
                                                      float* __restrict__ out,
                                                      float* __restrict__ pacc,
                                                      float2* __restrict__ pstats,
                                                      int chs, int ncs, int direct) {
    __shared__ __align__(16) char SMEM[131072];
    char* Kb = SMEM;                 // 32KB
    char* Vt0 = SMEM + 32768;        // 32KB
    char* Vt1 = SMEM + 65536;        // 32KB
    char* Pb = SMEM + 98304;         // 32KB
    const int t = threadIdx.x;
    const int lane = t & 63;
    const int w = t >> 6;            // 0..7

    const int b = blockIdx.x;
    const int c = b & ((1 << ncs) - 1);
    const int rest = b >> ncs;
    const int qtr = rest & 15;
    const int qt = 15 - qtr;                  // heavy q-tiles first
    const int n = rest >> 4;
    const int jtop = (qt << 2) + 3;           // last kv64 tile for this q256-tile
    const int jlo = c << chs;
    if (jlo > jtop) return;
    const int jhi = (jtop < jlo + (1 << chs) - 1) ? jtop : (jlo + (1 << chs) - 1);
    const int s0 = qt << 8;
    const int wr_direct = direct || ((jtop >> chs) == 0);

    // async stage K[64][256] bf16, 16B slots XOR (row&7), pre-swizzled global source
    auto stageK = [&](int j) {
        const int t0 = j << 6;
        #pragma unroll
        for (int i = 0; i < 4; ++i) {
            int rl = (i << 4) + (w << 1) + (lane >> 5);
            const short* src = (const short*)kg + ((long)(n * SS + t0 + rl)) * EE
                               + (((lane & 31) << 3) ^ ((rl & 7) << 3));
            GLOAD_LDS16(src, Kb + (i << 13) + (w << 10));
        }
    };
    // async stage V^T[256][64] bf16 from vo[n][o][s], 16B slots XOR (o&7)
    auto stageV = [&](int j, char* Vt) {
        const int t0 = j << 6;
        #pragma unroll
        for (int i = 0; i < 4; ++i) {
            int o = (i << 6) + (w << 3) + (lane >> 3);
            const short* src = (const short*)vg + ((long)((n << 8) + o)) * SS + t0
                               + (((lane & 7) << 3) ^ ((o & 7) << 3));
            GLOAD_LDS16(src, Vt + (i << 13) + (w << 10));
        }
    };

    // Q fragments in registers: 32 q-rows per wave (2 groups of 16)
    bf16x8 qf[2][8];
    #pragma unroll
    for (int g = 0; g < 2; ++g) {
        int qrow = s0 + (w << 5) + (g << 4) + (lane & 15);
        const short* qp = (const short*)qg + ((long)(n * SS + qrow)) * EE;
        #pragma unroll
        for (int kf = 0; kf < 8; ++kf)
            qf[g][kf] = *(const bf16x8*)(qp + ((lane >> 4) << 3) + (kf << 5));
    }

    float m_[2][4], ls[2][4];
    #pragma unroll
    for (int g = 0; g < 2; ++g)
        #pragma unroll
        for (int rr = 0; rr < 4; ++rr) { m_[g][rr] = -3e38f; ls[g][rr] = 0.f; }
    f32x4 acc[2][16];
    #pragma unroll
    for (int g = 0; g < 2; ++g)
        #pragma unroll
        for (int ocb = 0; ocb < 16; ++ocb) acc[g][ocb] = (f32x4){0.f, 0.f, 0.f, 0.f};

    stageK(jlo);
    stageV(jlo, (jlo & 1) ? Vt1 : Vt0);

    for (int j = jlo; j <= jhi; ++j) {
        char* Vc = (j & 1) ? Vt1 : Vt0;
        char* Vn = (j & 1) ? Vt0 : Vt1;
        const int t0 = j << 6;
        __syncthreads();   // [A] stages of tile j drained (vmcnt0+barrier)

        // ---- S = Q K^T : K-frag read once, used for both q-groups
        f32x4 sacc[2][4];
        #pragma unroll
        for (int g = 0; g < 2; ++g)
            #pragma unroll
            for (int cb = 0; cb < 4; ++cb) sacc[g][cb] = (f32x4){0.f, 0.f, 0.f, 0.f};
        #pragma unroll
        for (int cb = 0; cb < 4; ++cb) {
            int row = (cb << 4) + (lane & 15);
            #pragma unroll
            for (int kf = 0; kf < 8; ++kf) {
                int slot = (lane >> 4) + (kf << 2);
                bf16x8 kb = *(const bf16x8*)(Kb + row * 512 + ((slot ^ (row & 7)) << 4));
                sacc[0][cb] = __builtin_amdgcn_mfma_f32_16x16x32_bf16(qf[0][kf], kb, sacc[0][cb], 0, 0, 0);
                sacc[1][cb] = __builtin_amdgcn_mfma_f32_16x16x32_bf16(qf[1][kf], kb, sacc[1][cb], 0, 0, 0);
            }
        }

        __syncthreads();   // [B] all K reads done -> K restage is safe
        if (j < jhi) {     // issue next-tile stages; hide under softmax+PV
            stageK(j + 1);
            stageV(j + 1, Vn);
        }

        if ((j >> 2) == qt) {  // causal mask (diagonal spans kv64 tiles 4qt..4qt+3)
            #pragma unroll
            for (int cb = 0; cb < 4; ++cb) {
                int key = t0 + (cb << 4) + (lane & 15);
                #pragma unroll
                for (int g = 0; g < 2; ++g)
                    #pragma unroll
                    for (int rr = 0; rr < 4; ++rr) {
                        int qr = s0 + (w << 5) + (g << 4) + ((lane >> 4) << 2) + rr;
                        if (key > qr) sacc[g][cb][rr] = -1e30f;
                    }
            }
        }

        // ---- online softmax (8 rows' chains interleaved), defer-max (T13, THR=8)
        float mx[2][4];
        #pragma unroll
        for (int g = 0; g < 2; ++g)
            #pragma unroll
            for (int rr = 0; rr < 4; ++rr)
                mx[g][rr] = fmaxf(fmaxf(sacc[g][0][rr], sacc[g][1][rr]),
                                  fmaxf(sacc[g][2][rr], sacc[g][3][rr]));
        #pragma unroll
        for (int off = 1; off < 16; off <<= 1)
            #pragma unroll
            for (int g = 0; g < 2; ++g)
                #pragma unroll
                for (int rr = 0; rr < 4; ++rr) mx[g][rr] = fmaxf(mx[g][rr], __shfl_xor(mx[g][rr], off));

        bool ok = true;
        #pragma unroll
        for (int g = 0; g < 2; ++g)
            #pragma unroll
            for (int rr = 0; rr < 4; ++rr) ok = ok && (mx[g][rr] - m_[g][rr] <= 8.0f);
        if (!__all(ok)) {  // rescale path (rare)
            float scl[2][4];
            #pragma unroll
            for (int g = 0; g < 2; ++g)
                #pragma unroll
                for (int rr = 0; rr < 4; ++rr) {
                    float mn = fmaxf(m_[g][rr], mx[g][rr]);
                    scl[g][rr] = exp2f(m_[g][rr] - mn);
                    m_[g][rr] = mn;
                    ls[g][rr] *= scl[g][rr];
                }
            #pragma unroll
            for (int g = 0; g < 2; ++g)
                #pragma unroll
                for (int ocb = 0; ocb < 16; ++ocb)
                    #pragma unroll
                    for (int rr = 0; rr < 4; ++rr) acc[g][ocb][rr] *= scl[g][rr];
        }

        float pv[2][4][4], ps[2][4];
        #pragma unroll
        for (int g = 0; g < 2; ++g)
            #pragma unroll
            for (int cb = 0; cb < 4; ++cb)
                #pragma unroll
                for (int rr = 0; rr < 4; ++rr) pv[g][cb][rr] = exp2f(sacc[g][cb][rr] - m_[g][rr]);
        #pragma unroll
        for (int g = 0; g < 2; ++g)
            #pragma unroll
            for (int rr = 0; rr < 4; ++rr)
                ps[g][rr] = (pv[g][0][rr] + pv[g][1][rr]) + (pv[g][2][rr] + pv[g][3][rr]);
        #pragma unroll
        for (int off = 1; off < 16; off <<= 1)
            #pragma unroll
            for (int g = 0; g < 2; ++g)
                #pragma unroll
                for (int rr = 0; rr < 4; ++rr) ps[g][rr] += __shfl_xor(ps[g][rr], off);
        #pragma unroll
        for (int g = 0; g < 2; ++g)
            #pragma unroll
            for (int rr = 0; rr < 4; ++rr) ls[g][rr] += ps[g][rr];

        // ---- P -> per-wave LDS (rows 32, 128B rows, 16B-slot XOR (row&7))
        #pragma unroll
        for (int g = 0; g < 2; ++g)
            #pragma unroll
            for (int cb = 0; cb < 4; ++cb)
                #pragma unroll
                for (int rr = 0; rr < 4; ++rr) {
                    int row = (g << 4) + ((lane >> 4) << 2) + rr;
                    int col = (cb << 4) + (lane & 15);
                    *(__bf16*)(Pb + (w << 12) + (row << 7)
                               + (((col >> 3) ^ (row & 7)) << 4) + ((col & 7) << 1)) = (__bf16)pv[g][cb][rr];
                }

        // ---- PV: V-frag read once, used for both q-groups
        bf16x8 pa[2][2];
        #pragma unroll
        for (int g = 0; g < 2; ++g)
            #pragma unroll
            for (int kf2 = 0; kf2 < 2; ++kf2) {
                int row = (g << 4) + (lane & 15);
                int slot = (lane >> 4) + (kf2 << 2);
                pa[g][kf2] = *(const bf16x8*)(Pb + (w << 12) + (row << 7) + ((slot ^ (row & 7)) << 4));
            }
        #pragma unroll
        for (int ocb = 0; ocb < 16; ++ocb) {
            int orow = (ocb << 4) + (lane & 15);
            #pragma unroll
            for (int kf2 = 0; kf2 < 2; ++kf2) {
                int slot = (lane >> 4) + (kf2 << 2);
                bf16x8 vb = *(const bf16x8*)(Vc + (orow << 7) + ((slot ^ (orow & 7)) << 4));
                acc[0][ocb] = __builtin_amdgcn_mfma_f32_16x16x32_bf16(pa[0][kf2], vb, acc[0][ocb], 0, 0, 0);
                acc[1][ocb] = __builtin_amdgcn_mfma_f32_16x16x32_bf16(pa[1][kf2], vb, acc[1][ocb], 0, 0, 0);
            }
        }
    }

    // ---- per-row stats (partial mode only)
    if (!wr_direct && (lane & 15) == 0) {
        #pragma unroll
        for (int g = 0; g < 2; ++g)
            #pragma unroll
            for (int rr = 0; rr < 4; ++rr) {
                int s = (w << 5) + (g << 4) + ((lane >> 4) << 2) + rr;
                pstats[(long)b * 256 + s] = make_float2(m_[g][rr], ls[g][rr]);
            }
    }

    // ---- epilogue: per-og transpose via LDS T[32][260] f32, coalesced writes
    float inv[2][4];
    #pragma unroll
    for (int g = 0; g < 2; ++g)
        #pragma unroll
        for (int rr = 0; rr < 4; ++rr) inv[g][rr] = wr_direct ? (1.0f / ls[g][rr]) : 1.0f;
    float* T = (float*)SMEM;  // 33.3KB, fits Kb+Vt0

#define EPI_STAGE(og)                                                                   \
    do {                                                                                \
        __syncthreads();                                                                \
        _Pragma("unroll")                                                               \
        for (int e = 0; e < 2; ++e) {                                                   \
            _Pragma("unroll")                                                           \
            for (int g = 0; g < 2; ++g) {                                               \
                _Pragma("unroll")                                                       \
                for (int rr = 0; rr < 4; ++rr) {                                        \
                    int rw = (e << 4) + (lane & 15);                                    \
                    int cl = (w << 5) + (g << 4) + ((lane >> 4) << 2) + rr;             \
                    T[rw * 260 + cl] = acc[g][((og) << 1) + e][rr] * inv[g][rr];        \
                }                                                                       \
            }                                                                           \
        }                                                                               \
        __syncthreads();                                                                \
        {                                                                               \
            int row = t >> 4;                                                           \
            _Pragma("unroll")                                                           \
            for (int u = 0; u < 4; ++u) {                                               \
                int col = ((t & 15) << 2) + (u << 6);                                   \
                f32x4 r = *(const f32x4*)(T + row * 260 + col);                         \
                float* dp = wr_direct                                                   \
                    ? (out + ((long)((n << 8) + ((og) << 5) + row)) * SS + s0 + col)    \
                    : (pacc + ((long)b << 16) + ((((og) << 5) + row) << 8) + col);      \
                *(f32x4*)dp = r;                                                        \
            }                                                                           \
        }                                                                               \
    } while (0)

    EPI_STAGE(0); EPI_STAGE(1); EPI_STAGE(2); EPI_STAGE(3);
    EPI_STAGE(4); EPI_STAGE(5); EPI_STAGE(6); EPI_STAGE(7);
#undef EPI_STAGE
}

// ---------------- combine partials (skip single-chunk q-tiles) ----------------
__global__ __launch_bounds__(256) void combine_kernel(const float* __restrict__ pacc,
                                                      const float2* __restrict__ pstats,
                                                      float* __restrict__ out,
                                                      int chs, int ncs) {
    const int t = threadIdx.x;
    const int b2 = blockIdx.x;
    const int og = b2 & 7;
    const int qtr = (b2 >> 3) & 15;
    const int qt = 15 - qtr;
    const int n = b2 >> 7;
    const int jtop = (qt << 2) + 3;
    const int nch = (jtop >> chs) + 1;
    if (nch == 1) return;
    const long sb0 = (long)(((n << 4) + qtr) << ncs);

    __shared__ float wsc[8][256];
    __shared__ float invL[256];
    {
        int s = t;
        float M = -3e38f;
        for (int c2 = 0; c2 < nch; ++c2) M = fmaxf(M, pstats[(sb0 + c2) * 256 + s].x);
        float L = 0.f;
        for (int c2 = 0; c2 < nch; ++c2) {
            float2 st = pstats[(sb0 + c2) * 256 + s];
            float wv = exp2f(st.x - M);
            wsc[c2][s] = wv;
            L += st.y * wv;
        }
        invL[s] = 1.f / L;
    }
    __syncthreads();

    const int o = (og << 5) + (t >> 3);
    const int sc = (t & 7) << 5;
    float a[32];
    #pragma unroll
    for (int i = 0; i < 32; ++i) a[i] = 0.f;
    for (int c2 = 0; c2 < nch; ++c2) {
        const float* p = pacc + ((sb0 + c2) << 16) + (o << 8) + sc;
        #pragma unroll
        for (int u = 0; u < 8; ++u) {
            f32x4 v = *(const f32x4*)(p + (u << 2));
            #pragma unroll
            for (int k2 = 0; k2 < 4; ++k2) a[(u << 2) + k2] += v[k2] * wsc[c2][sc + (u << 2) + k2];
        }
    }
    float* op = out + ((long)((n << 8) + o)) * SS + (qt << 8) + sc;
    #pragma unroll
    for (int u = 0; u < 8; ++u) {
        f32x4 r;
        #pragma unroll
        for (int k2 = 0; k2 < 4; ++k2) r[k2] = a[(u << 2) + k2] * invL[sc + (u << 2) + k2];
        *(f32x4*)(op + (u << 2)) = r;
    }
}

extern "C" void kernel_launch(void* const* d_in, const int* in_sizes, int n_in,
                              void* d_out, int out_size, void* d_ws, size_t ws_size,
                              hipStream_t stream) {
    const float* x   = (const float*)d_in[0];
    const float* Wq  = (const float*)d_in[1];
    const float* bq  = (const float*)d_in[2];
    const float* Wkv = (const float*)d_in[3];
    const float* bkv = (const float*)d_in[4];
    float* out = (float*)d_out;
    char* ws = (char*)d_ws;
    __bf16* qw = (__bf16*)(ws + QOFF);
    __bf16* kw = (__bf16*)(ws + KOFF);
    __bf16* vw = (__bf16*)(ws + VOFF);
    __bf16* wc = (__bf16*)(ws + WOFF);
    float*  bias = (float*)(ws + BOFF);

    // split-KV: 512 slots x (256o x 256s f32) partials + stats
    size_t need = (size_t)PAOFF + (size_t)512 * 262144 + (size_t)512 * 2048;
    int direct = (ws_size < need) ? 1 : 0;
    int ncs = direct ? 0 : 3;     // chunks per q-tile (log2)
    int chs = direct ? 6 : 3;     // kv64 tiles per chunk (log2)
    float* pacc = (float*)(ws + PAOFF);
    float2* pstats = (float2*)(ws + PAOFF + (size_t)512 * 262144);

    prep_kernel<<<dim3(768), dim3(256), 0, stream>>>(Wq, bq, Wkv, bkv, wc, bias);
    proj_kernel<<<dim3(256), dim3(256), 0, stream>>>(x, wc, bias, qw, kw, vw);
    attn_kernel<<<dim3(64 << ncs), dim3(512), 0, stream>>>(qw, kw, vw, out, pacc, pstats,
                                                           chs, ncs, direct);
    if (!direct)
        combine_kernel<<<dim3(512), dim3(256), 0, stream>>>(pacc, pstats, out, chs, ncs);
}

// Round 8
// 376.603 us; speedup vs baseline: 1.0055x; 1.0055x over previous
//
#include <hip/hip_runtime.h>
#include <hip/hip_bf16.h>

typedef __bf16 bf16x8 __attribute__((ext_vector_type(8)));
typedef float f32x4 __attribute__((ext_vector_type(4)));
typedef short short8 __attribute__((ext_vector_type(8)));
typedef short short4v __attribute__((ext_vector_type(4)));

#define NB 4
#define CC 256
#define SS 4096
#define EE 256

static constexpr float QSCALE = 1.4426950408889634f / 16.0f;  // log2(e)/sqrt(E)

// workspace offsets (bytes)
#define QOFF 0u
#define KOFF 8388608u
#define VOFF 16777216u
#define WOFF 25165824u
#define BOFF 25559040u
#define PAOFF 25690112u   // partial acc f32 [slot][256 o][128 s], then stats float2 [slot][128 s]

#define GLOAD_LDS16(gsrc, ldst) \
    __builtin_amdgcn_global_load_lds((const __attribute__((address_space(1))) void*)(gsrc), \
                                     (__attribute__((address_space(3))) void*)(ldst), 16, 0, 0)

// ---------------- weight prep: fp32 -> bf16 (q rows pre-scaled) ----------------
__global__ __launch_bounds__(256) void prep_kernel(const float* __restrict__ Wq,
                                                   const float* __restrict__ bq,
                                                   const float* __restrict__ Wkv,
                                                   const float* __restrict__ bkv,
                                                   __bf16* __restrict__ wc,
                                                   float* __restrict__ bias) {
    int r = blockIdx.x;
    int t = threadIdx.x;
    float v;
    if (r < 256) v = Wq[r * 256 + t] * QSCALE;
    else         v = Wkv[(r - 256) * 256 + t];
    wc[r * 256 + t] = (__bf16)v;
    if (t == 0) bias[r] = (r < 256) ? bq[r] * QSCALE : bkv[r - 256];
}

// ---------------- projection: q,k [n][S][E] bf16 ; v transposed [n][O][S] bf16 ----------------
__global__ __launch_bounds__(256) void proj_kernel(const float* __restrict__ x,
                                                   const __bf16* __restrict__ wc,
                                                   const float* __restrict__ bias,
                                                   __bf16* __restrict__ qo,
                                                   __bf16* __restrict__ ko,
                                                   __bf16* __restrict__ vo) {
    __shared__ __align__(16) char Ab[32768];
    __shared__ __align__(16) char Wb[32768];
    const int t = threadIdx.x;
    const int lane = t & 63;
    const int w = t >> 6;
    const int n = blockIdx.x >> 6;
    const int s0 = (blockIdx.x & 63) << 6;

    {
        const int sl = t & 15;
        const int cc0 = t >> 4;
        #pragma unroll
        for (int it = 0; it < 2; ++it) {
            int c0 = (cc0 + (it << 4)) << 3;
            float f[8][4];
            #pragma unroll
            for (int r = 0; r < 8; ++r) {
                const float* xp = x + ((long)(n * CC + c0 + r)) * SS + s0 + sl;
                #pragma unroll
                for (int i = 0; i < 4; ++i) f[r][i] = xp[i << 4];
            }
            #pragma unroll
            for (int i = 0; i < 4; ++i) {
                bf16x8 v;
                #pragma unroll
                for (int r = 0; r < 8; ++r) v[r] = (__bf16)f[r][i];
                int srow = sl + (i << 4);
                *(bf16x8*)(Ab + srow * 512 + ((c0 * 2) ^ ((srow & 7) << 4))) = v;
            }
        }
    }
    __syncthreads();

    bf16x8 af[8];
    {
        int arow = (w << 4) + (lane & 15);
        #pragma unroll
        for (int kf = 0; kf < 8; ++kf) {
            int c = ((lane >> 4) << 3) + (kf << 5);
            af[kf] = *(const bf16x8*)(Ab + arow * 512 + ((c * 2) ^ ((arow & 7) << 4)));
        }
    }

    for (int ot = 0; ot < 12; ++ot) {
        #pragma unroll
        for (int p = 0; p < 16; ++p) {
            int row = w + (p << 2);
            int c = lane << 2;
            short4v vv = *(const short4v*)((const short*)wc + (ot * 64 + row) * 256 + c);
            *(short4v*)(Wb + row * 512 + ((c * 2) ^ ((row & 7) << 4))) = vv;
        }
        __syncthreads();

        f32x4 acc[4];
        #pragma unroll
        for (int cb = 0; cb < 4; ++cb) acc[cb] = (f32x4){0.f, 0.f, 0.f, 0.f};
        #pragma unroll
        for (int cb = 0; cb < 4; ++cb) {
            int row = (cb << 4) + (lane & 15);
            #pragma unroll
            for (int kf = 0; kf < 8; ++kf) {
                int c = ((lane >> 4) << 3) + (kf << 5);
                bf16x8 bfr = *(const bf16x8*)(Wb + row * 512 + ((c * 2) ^ ((row & 7) << 4)));
                acc[cb] = __builtin_amdgcn_mfma_f32_16x16x32_bf16(af[kf], bfr, acc[cb], 0, 0, 0);
            }
        }
        __syncthreads();

        __bf16* T = (__bf16*)Wb;
        float bsv[4];
        #pragma unroll
        for (int cb = 0; cb < 4; ++cb) bsv[cb] = bias[ot * 64 + (cb << 4) + (lane & 15)];

        if (ot < 8) {
            #pragma unroll
            for (int cb = 0; cb < 4; ++cb) {
                #pragma unroll
                for (int jj = 0; jj < 4; ++jj) {
                    int srow = (w << 4) + ((lane >> 4) << 2) + jj;
                    T[srow * 72 + (cb << 4) + (lane & 15)] = (__bf16)(acc[cb][jj] + bsv[cb]);
                }
            }
            __syncthreads();
            int s = t >> 2;
            int o0 = (t & 3) << 4;
            short8 r0 = *(const short8*)((const short*)T + s * 72 + o0);
            short8 r1 = *(const short8*)((const short*)T + s * 72 + o0 + 8);
            __bf16* dst = (ot < 4) ? qo : ko;
            long idx = ((long)(n * SS + s0 + s)) * EE + ((ot & 3) << 6) + o0;
            *(short8*)((short*)dst + idx) = r0;
            *(short8*)((short*)dst + idx + 8) = r1;
        } else {
            #pragma unroll
            for (int cb = 0; cb < 4; ++cb) {
                #pragma unroll
                for (int jj = 0; jj < 4; ++jj) {
                    int srow = (w << 4) + ((lane >> 4) << 2) + jj;
                    T[((cb << 4) + (lane & 15)) * 72 + srow] = (__bf16)(acc[cb][jj] + bsv[cb]);
                }
            }
            __syncthreads();
            int o = t >> 2;
            int sc0 = (t & 3) << 4;
            short8 r0 = *(const short8*)((const short*)T + o * 72 + sc0);
            short8 r1 = *(const short8*)((const short*)T + o * 72 + sc0 + 8);
            long idx = ((long)((n << 8) + ((ot - 8) << 6) + o)) * SS + s0 + sc0;
            *(short8*)((short*)vo + idx) = r0;
            *(short8*)((short*)vo + idx + 8) = r1;
        }
        __syncthreads();
    }
}

// ---------------- causal flash attention: QBLK=128 (8 waves x 16q), KVBLK=64, R5 schedule ----------------
// LDS (80KB = 2 blocks/CU): K[64][256] 32KB | V^T[256][64] 32KB | P[8][16][64] swz 16KB
__global__ __launch_bounds__(512, 4) void attn_kernel(const __bf16* __restrict__ qg,
                                                      const __bf16* __restrict__ kg,
                                                      const __bf16* __restrict__ vg,
                                                      float* __restrict__ out,
                                                      float* __restrict__ pacc,
                                                      float2* __restrict__ pstats,
                                                      int chs, int ncs, int direct) {
    __shared__ __align__(16) char SMEM[81920];
    char* Kb = SMEM;                 // 32KB
    char* Vt = SMEM + 32768;         // 32KB
    char* Pb = SMEM + 65536;         // 16KB (2KB per wave)
    const int t = threadIdx.x;
    const int lane = t & 63;
    const int w = t >> 6;            // 0..7

    const int b = blockIdx.x;
    const int c = b & ((1 << ncs) - 1);
    const int rest = b >> ncs;
    const int qtr = rest & 31;
    const int qt = 31 - qtr;                  // heavy q-tiles first
    const int n = rest >> 5;
    const int jtop = (qt << 1) + 1;           // last kv64 tile for this q128-tile
    const int jlo = c << chs;
    if (jlo > jtop) return;
    const int jhi = (jtop < jlo + (1 << chs) - 1) ? jtop : (jlo + (1 << chs) - 1);
    const int s0 = qt << 7;
    const int wr_direct = direct || ((jtop >> chs) == 0);

    // async stage K[64][256] bf16, 16B slots XOR (row&7); linear LDS dest, pre-swizzled source
    auto stageK = [&](int j) {
        const int t0 = j << 6;
        #pragma unroll
        for (int i = 0; i < 4; ++i) {
            int rl = (i << 4) + (w << 1) + (lane >> 5);
            const short* src = (const short*)kg + ((long)(n * SS + t0 + rl)) * EE
                               + (((lane & 31) << 3) ^ ((rl & 7) << 3));
            GLOAD_LDS16(src, Kb + ((i << 4) + (w << 1)) * 512);
        }
    };
    // async stage V^T[256][64] bf16 from vo[n][o][s], 16B slots XOR (o&7)
    auto stageV = [&](int j) {
        const int t0 = j << 6;
        #pragma unroll
        for (int i = 0; i < 4; ++i) {
            int o = (i << 6) + (w << 3) + (lane >> 3);
            const short* src = (const short*)vg + ((long)((n << 8) + o)) * SS + t0
                               + (((lane & 7) << 3) ^ ((o & 7) << 3));
            GLOAD_LDS16(src, Vt + ((i << 6) + (w << 3)) * 128);
        }
    };

    // Q fragments in registers (16 q-rows per wave)
    bf16x8 qf[8];
    {
        int qrow = s0 + (w << 4) + (lane & 15);
        const short* qp = (const short*)qg + ((long)(n * SS + qrow)) * EE;
        #pragma unroll
        for (int kf = 0; kf < 8; ++kf)
            qf[kf] = *(const bf16x8*)(qp + ((lane >> 4) << 3) + (kf << 5));
    }

    float m_[4], ls[4];
    #pragma unroll
    for (int rr = 0; rr < 4; ++rr) { m_[rr] = -3e38f; ls[rr] = 0.f; }
    f32x4 acc[16];
    #pragma unroll
    for (int ocb = 0; ocb < 16; ++ocb) acc[ocb] = (f32x4){0.f, 0.f, 0.f, 0.f};

    stageK(jlo);
    stageV(jlo);

    for (int j = jlo; j <= jhi; ++j) {
        const int t0 = j << 6;
        __syncthreads();   // drains vmcnt: stage(j) resident in LDS

        // ---- S = Q K^T (16 q x 64 k per wave)
        f32x4 sacc[4];
        #pragma unroll
        for (int cb = 0; cb < 4; ++cb) sacc[cb] = (f32x4){0.f, 0.f, 0.f, 0.f};
        #pragma unroll
        for (int cb = 0; cb < 4; ++cb) {
            int row = (cb << 4) + (lane & 15);
            #pragma unroll
            for (int kf = 0; kf < 8; ++kf) {
                int slot = (lane >> 4) + (kf << 2);
                bf16x8 kb = *(const bf16x8*)(Kb + row * 512 + ((slot ^ (row & 7)) << 4));
                sacc[cb] = __builtin_amdgcn_mfma_f32_16x16x32_bf16(qf[kf], kb, sacc[cb], 0, 0, 0);
            }
        }

        if ((j >> 1) == qt) {   // causal mask (diagonal spans kv64 tiles 2qt, 2qt+1)
            #pragma unroll
            for (int cb = 0; cb < 4; ++cb) {
                int key = t0 + (cb << 4) + (lane & 15);
                #pragma unroll
                for (int rr = 0; rr < 4; ++rr) {
                    int qr = s0 + (w << 4) + ((lane >> 4) << 2) + rr;
                    if (key > qr) sacc[cb][rr] = -1e30f;
                }
            }
        }

        // ---- online softmax, 4 rows' reduction chains interleaved
        float mx[4], ps[4], scl[4];
        #pragma unroll
        for (int rr = 0; rr < 4; ++rr)
            mx[rr] = fmaxf(fmaxf(sacc[0][rr], sacc[1][rr]), fmaxf(sacc[2][rr], sacc[3][rr]));
        #pragma unroll
        for (int off = 1; off < 16; off <<= 1) {
            #pragma unroll
            for (int rr = 0; rr < 4; ++rr) mx[rr] = fmaxf(mx[rr], __shfl_xor(mx[rr], off));
        }
        float pv[4][4];
        #pragma unroll
        for (int rr = 0; rr < 4; ++rr) {
            float mn = fmaxf(m_[rr], mx[rr]);
            scl[rr] = exp2f(m_[rr] - mn);
            m_[rr] = mn;
        }
        #pragma unroll
        for (int cb = 0; cb < 4; ++cb)
            #pragma unroll
            for (int rr = 0; rr < 4; ++rr) pv[cb][rr] = exp2f(sacc[cb][rr] - m_[rr]);
        #pragma unroll
        for (int rr = 0; rr < 4; ++rr)
            ps[rr] = (pv[0][rr] + pv[1][rr]) + (pv[2][rr] + pv[3][rr]);
        #pragma unroll
        for (int off = 1; off < 16; off <<= 1) {
            #pragma unroll
            for (int rr = 0; rr < 4; ++rr) ps[rr] += __shfl_xor(ps[rr], off);
        }
        #pragma unroll
        for (int rr = 0; rr < 4; ++rr) ls[rr] = ls[rr] * scl[rr] + ps[rr];

        // ---- P -> per-wave LDS (16 rows x 128B, 16B-slot XOR (row&7))
        #pragma unroll
        for (int cb = 0; cb < 4; ++cb)
            #pragma unroll
            for (int rr = 0; rr < 4; ++rr) {
                int row = ((lane >> 4) << 2) + rr;
                int col = (cb << 4) + (lane & 15);
                *(__bf16*)(Pb + (w << 11) + (row << 7)
                           + (((col >> 3) ^ (row & 7)) << 4) + ((col & 7) << 1)) = (__bf16)pv[cb][rr];
            }

        #pragma unroll
        for (int ocb = 0; ocb < 16; ++ocb)
            #pragma unroll
            for (int rr = 0; rr < 4; ++rr) acc[ocb][rr] *= scl[rr];

        // ---- PV: P (own-wave LDS) x V^T (LDS)
        bf16x8 pa[2];
        #pragma unroll
        for (int kf2 = 0; kf2 < 2; ++kf2) {
            int prow = lane & 15;
            int pslot = (lane >> 4) + (kf2 << 2);
            pa[kf2] = *(const bf16x8*)(Pb + (w << 11) + (prow << 7) + ((pslot ^ (prow & 7)) << 4));
        }
        #pragma unroll
        for (int ocb = 0; ocb < 16; ++ocb) {
            int orow = (ocb << 4) + (lane & 15);
            #pragma unroll
            for (int kf2 = 0; kf2 < 2; ++kf2) {
                int slot = (lane >> 4) + (kf2 << 2);
                bf16x8 vb = *(const bf16x8*)(Vt + (orow << 7) + ((slot ^ (orow & 7)) << 4));
                acc[ocb] = __builtin_amdgcn_mfma_f32_16x16x32_bf16(pa[kf2], vb, acc[ocb], 0, 0, 0);
            }
        }

        __syncthreads();   // all Kb/Vt reads done; safe to restage
        if (j < jhi) {     // issue next-tile stage; drained at next top-of-loop barrier
            stageK(j + 1);
            stageV(j + 1);
        }
    }

    // ---- per-row stats (partial mode only)
    if (!wr_direct && (lane & 15) == 0) {
        #pragma unroll
        for (int rr = 0; rr < 4; ++rr) {
            int s = (w << 4) + ((lane >> 4) << 2) + rr;
            pstats[(long)b * 128 + s] = make_float2(m_[rr], ls[rr]);
        }
    }

    // ---- epilogue: 8 stages of 32 o-rows; transpose via LDS T[32][132] f32 (reuse SMEM)
    float inv[4];
    #pragma unroll
    for (int rr = 0; rr < 4; ++rr) inv[rr] = wr_direct ? (1.0f / ls[rr]) : 1.0f;
    float* T = (float*)SMEM;  // 32*132*4 = 16.9KB

#define EPI_STAGE(g)                                                                    \
    do {                                                                                \
        __syncthreads();                                                                \
        _Pragma("unroll")                                                               \
        for (int e = 0; e < 2; ++e) {                                                   \
            _Pragma("unroll")                                                           \
            for (int rr = 0; rr < 4; ++rr) {                                            \
                int ol = (e << 4) + (lane & 15);                                        \
                int cl = (w << 4) + ((lane >> 4) << 2) + rr;                            \
                T[ol * 132 + cl] = acc[((g) << 1) + e][rr] * inv[rr];                   \
            }                                                                           \
        }                                                                               \
        __syncthreads();                                                                \
        {                                                                               \
            int row = t >> 4;                  /* 0..31 */                              \
            int c0 = (t & 15) << 3;            /* 8 f32 per thread */                   \
            float* dp = wr_direct                                                       \
                ? (out + ((long)((n << 8) + ((g) << 5) + row)) * SS + s0 + c0)          \
                : (pacc + ((long)b << 15) + ((((g) << 5) + row) << 7) + c0);            \
            f32x4 r0 = *(const f32x4*)(T + row * 132 + c0);                             \
            f32x4 r1 = *(const f32x4*)(T + row * 132 + c0 + 4);                         \
            *(f32x4*)dp = r0;                                                           \
            *(f32x4*)(dp + 4) = r1;                                                     \
        }                                                                               \
    } while (0)

    EPI_STAGE(0); EPI_STAGE(1); EPI_STAGE(2); EPI_STAGE(3);
    EPI_STAGE(4); EPI_STAGE(5); EPI_STAGE(6); EPI_STAGE(7);
#undef EPI_STAGE
}

// ---------------- combine partials (skip single-chunk q-tiles: written direct) ----------------
__global__ __launch_bounds__(256) void combine_kernel(const float* __restrict__ pacc,
                                                      const float2* __restrict__ pstats,
                                                      float* __restrict__ out,
                                                      int chs, int ncs) {
    const int t = threadIdx.x;
    const int b2 = blockIdx.x;
    const int og = b2 & 7;               // 32-o slice
    const int qtr = (b2 >> 3) & 31;
    const int qt = 31 - qtr;
    const int n = b2 >> 8;
    const int jtop = (qt << 1) + 1;
    const int nch = (jtop >> chs) + 1;
    if (nch == 1) return;
    const long sb0 = (long)(((n << 5) + qtr) << ncs);

    __shared__ float wsc[8][128];
    __shared__ float invL[128];
    if (t < 128) {
        float M = -3e38f;
        for (int c2 = 0; c2 < nch; ++c2) M = fmaxf(M, pstats[(sb0 + c2) * 128 + t].x);
        float L = 0.f;
        for (int c2 = 0; c2 < nch; ++c2) {
            float2 st = pstats[(sb0 + c2) * 128 + t];
            float wv = exp2f(st.x - M);
            wsc[c2][t] = wv;
            L += st.y * wv;
        }
        invL[t] = 1.f / L;
    }
    __syncthreads();

    const int o = (og << 5) + (t >> 3);  // 32 o-rows
    const int sc = (t & 7) << 4;         // 16 f32 per thread
    float a[16];
    #pragma unroll
    for (int i = 0; i < 16; ++i) a[i] = 0.f;
    for (int c2 = 0; c2 < nch; ++c2) {
        const float* p = pacc + ((sb0 + c2) << 15) + (o << 7) + sc;
        #pragma unroll
        for (int u = 0; u < 4; ++u) {
            f32x4 v = *(const f32x4*)(p + (u << 2));
            #pragma unroll
            for (int k2 = 0; k2 < 4; ++k2) a[(u << 2) + k2] += v[k2] * wsc[c2][sc + (u << 2) + k2];
        }
    }
    float* op = out + ((long)((n << 8) + o)) * SS + (qt << 7) + sc;
    #pragma unroll
    for (int u = 0; u < 4; ++u) {
        f32x4 r;
        #pragma unroll
        for (int k2 = 0; k2 < 4; ++k2) r[k2] = a[(u << 2) + k2] * invL[sc + (u << 2) + k2];
        *(f32x4*)(op + (u << 2)) = r;
    }
}

extern "C" void kernel_launch(void* const* d_in, const int* in_sizes, int n_in,
                              void* d_out, int out_size, void* d_ws, size_t ws_size,
                              hipStream_t stream) {
    const float* x   = (const float*)d_in[0];
    const float* Wq  = (const float*)d_in[1];
    const float* bq  = (const float*)d_in[2];
    const float* Wkv = (const float*)d_in[3];
    const float* bkv = (const float*)d_in[4];
    float* out = (float*)d_out;
    char* ws = (char*)d_ws;
    __bf16* qw = (__bf16*)(ws + QOFF);
    __bf16* kw = (__bf16*)(ws + KOFF);
    __bf16* vw = (__bf16*)(ws + VOFF);
    __bf16* wc = (__bf16*)(ws + WOFF);
    float*  bias = (float*)(ws + BOFF);

    // split-KV: 1024 slots x (256o x 128s f32) partials + stats
    size_t need = (size_t)PAOFF + (size_t)1024 * 131072 + (size_t)1024 * 1024;
    int direct = (ws_size < need) ? 1 : 0;
    int ncs = direct ? 0 : 3;     // chunks per q128-tile (log2)
    int chs = direct ? 6 : 3;     // kv64 tiles per chunk (log2)
    float* pacc = (float*)(ws + PAOFF);
    float2* pstats = (float2*)(ws + PAOFF + (size_t)1024 * 131072);

    prep_kernel<<<dim3(768), dim3(256), 0, stream>>>(Wq, bq, Wkv, bkv, wc, bias);
    proj_kernel<<<dim3(256), dim3(256), 0, stream>>>(x, wc, bias, qw, kw, vw);
    attn_kernel<<<dim3(128 << ncs), dim3(512), 0, stream>>>(qw, kw, vw, out, pacc, pstats,
                                                            chs, ncs, direct);
    if (!direct)
        combine_kernel<<<dim3(1024), dim3(256), 0, stream>>>(pacc, pstats, out, chs, ncs);
}

// Round 10
// 199.144 us; speedup vs baseline: 1.9015x; 1.8911x over previous
//
#include <hip/hip_runtime.h>
#include <hip/hip_bf16.h>

typedef __bf16 bf16x8 __attribute__((ext_vector_type(8)));
typedef float f32x4 __attribute__((ext_vector_type(4)));
typedef short short8 __attribute__((ext_vector_type(8)));
typedef short short4v __attribute__((ext_vector_type(4)));

#define NB 4
#define CC 256
#define SS 4096
#define EE 256

static constexpr float QSCALE = 1.4426950408889634f / 16.0f;  // log2(e)/sqrt(E)

// workspace offsets (bytes)
#define QOFF 0u
#define KOFF 8388608u
#define VOFF 16777216u
#define WOFF 25165824u
#define BOFF 25559040u
#define PAOFF 25690112u   // partial acc f32 [slot][256 o][128 s], then stats float2 [slot][128 s]

#define GLOAD_LDS16(gsrc, ldst) \
    __builtin_amdgcn_global_load_lds((const __attribute__((address_space(1))) void*)(gsrc), \
                                     (__attribute__((address_space(3))) void*)(ldst), 16, 0, 0)

// ---------------- weight prep: fp32 -> bf16 (q rows pre-scaled) ----------------
__global__ __launch_bounds__(256) void prep_kernel(const float* __restrict__ Wq,
                                                   const float* __restrict__ bq,
                                                   const float* __restrict__ Wkv,
                                                   const float* __restrict__ bkv,
                                                   __bf16* __restrict__ wc,
                                                   float* __restrict__ bias) {
    int r = blockIdx.x;
    int t = threadIdx.x;
    float v;
    if (r < 256) v = Wq[r * 256 + t] * QSCALE;
    else         v = Wkv[(r - 256) * 256 + t];
    wc[r * 256 + t] = (__bf16)v;
    if (t == 0) bias[r] = (r < 256) ? bq[r] * QSCALE : bkv[r - 256];
}

// ---------------- projection: q,k [n][S][E] bf16 ; v transposed [n][O][S] bf16 ----------------
__global__ __launch_bounds__(256) void proj_kernel(const float* __restrict__ x,
                                                   const __bf16* __restrict__ wc,
                                                   const float* __restrict__ bias,
                                                   __bf16* __restrict__ qo,
                                                   __bf16* __restrict__ ko,
                                                   __bf16* __restrict__ vo) {
    __shared__ __align__(16) char Ab[32768];
    __shared__ __align__(16) char Wb[32768];
    const int t = threadIdx.x;
    const int lane = t & 63;
    const int w = t >> 6;
    const int n = blockIdx.x >> 6;
    const int s0 = (blockIdx.x & 63) << 6;

    {
        const int sl = t & 15;
        const int cc0 = t >> 4;
        #pragma unroll
        for (int it = 0; it < 2; ++it) {
            int c0 = (cc0 + (it << 4)) << 3;
            float f[8][4];
            #pragma unroll
            for (int r = 0; r < 8; ++r) {
                const float* xp = x + ((long)(n * CC + c0 + r)) * SS + s0 + sl;
                #pragma unroll
                for (int i = 0; i < 4; ++i) f[r][i] = xp[i << 4];
            }
            #pragma unroll
            for (int i = 0; i < 4; ++i) {
                bf16x8 v;
                #pragma unroll
                for (int r = 0; r < 8; ++r) v[r] = (__bf16)f[r][i];
                int srow = sl + (i << 4);
                *(bf16x8*)(Ab + srow * 512 + ((c0 * 2) ^ ((srow & 7) << 4))) = v;
            }
        }
    }
    __syncthreads();

    bf16x8 af[8];
    {
        int arow = (w << 4) + (lane & 15);
        #pragma unroll
        for (int kf = 0; kf < 8; ++kf) {
            int c = ((lane >> 4) << 3) + (kf << 5);
            af[kf] = *(const bf16x8*)(Ab + arow * 512 + ((c * 2) ^ ((arow & 7) << 4)));
        }
    }

    for (int ot = 0; ot < 12; ++ot) {
        #pragma unroll
        for (int p = 0; p < 16; ++p) {
            int row = w + (p << 2);
            int c = lane << 2;
            short4v vv = *(const short4v*)((const short*)wc + (ot * 64 + row) * 256 + c);
            *(short4v*)(Wb + row * 512 + ((c * 2) ^ ((row & 7) << 4))) = vv;
        }
        __syncthreads();

        f32x4 acc[4];
        #pragma unroll
        for (int cb = 0; cb < 4; ++cb) acc[cb] = (f32x4){0.f, 0.f, 0.f, 0.f};
        #pragma unroll
        for (int cb = 0; cb < 4; ++cb) {
            int row = (cb << 4) + (lane & 15);
            #pragma unroll
            for (int kf = 0; kf < 8; ++kf) {
                int c = ((lane >> 4) << 3) + (kf << 5);
                bf16x8 bfr = *(const bf16x8*)(Wb + row * 512 + ((c * 2) ^ ((row & 7) << 4)));
                acc[cb] = __builtin_amdgcn_mfma_f32_16x16x32_bf16(af[kf], bfr, acc[cb], 0, 0, 0);
            }
        }
        __syncthreads();

        __bf16* T = (__bf16*)Wb;
        float bsv[4];
        #pragma unroll
        for (int cb = 0; cb < 4; ++cb) bsv[cb] = bias[ot * 64 + (cb << 4) + (lane & 15)];

        if (ot < 8) {
            #pragma unroll
            for (int cb = 0; cb < 4; ++cb) {
                #pragma unroll
                for (int jj = 0; jj < 4; ++jj) {
                    int srow = (w << 4) + ((lane >> 4) << 2) + jj;
                    T[srow * 72 + (cb << 4) + (lane & 15)] = (__bf16)(acc[cb][jj] + bsv[cb]);
                }
            }
            __syncthreads();
            int s = t >> 2;
            int o0 = (t & 3) << 4;
            short8 r0 = *(const short8*)((const short*)T + s * 72 + o0);
            short8 r1 = *(const short8*)((const short*)T + s * 72 + o0 + 8);
            __bf16* dst = (ot < 4) ? qo : ko;
            long idx = ((long)(n * SS + s0 + s)) * EE + ((ot & 3) << 6) + o0;
            *(short8*)((short*)dst + idx) = r0;
            *(short8*)((short*)dst + idx + 8) = r1;
        } else {
            #pragma unroll
            for (int cb = 0; cb < 4; ++cb) {
                #pragma unroll
                for (int jj = 0; jj < 4; ++jj) {
                    int srow = (w << 4) + ((lane >> 4) << 2) + jj;
                    T[((cb << 4) + (lane & 15)) * 72 + srow] = (__bf16)(acc[cb][jj] + bsv[cb]);
                }
            }
            __syncthreads();
            int o = t >> 2;
            int sc0 = (t & 3) << 4;
            short8 r0 = *(const short8*)((const short*)T + o * 72 + sc0);
            short8 r1 = *(const short8*)((const short*)T + o * 72 + sc0 + 8);
            long idx = ((long)((n << 8) + ((ot - 8) << 6) + o)) * SS + s0 + sc0;
            *(short8*)((short*)vo + idx) = r0;
            *(short8*)((short*)vo + idx + 8) = r1;
        }
        __syncthreads();
    }
}

// ---------------- causal flash attention: QBLK=128 (8 waves), KVBLK=64, dbuf K+V, 1 barrier/tile ----------------
// LDS (144KB, 1 block/CU): K[2][64][256] 64KB | V^T[2][256][64] 64KB | P[8][16][64] swz 16KB
__global__ __launch_bounds__(512, 2) void attn_kernel(const __bf16* __restrict__ qg,
                                                      const __bf16* __restrict__ kg,
                                                      const __bf16* __restrict__ vg,
                                                      float* __restrict__ out,
                                                      float* __restrict__ pacc,
                                                      float2* __restrict__ pstats,
                                                      int chs, int ncs, int direct) {
    __shared__ __align__(16) char SMEM[147456];
    // buffer pointers derived arithmetically from parity (NO pointer arrays into LDS:
    // static-initializer addrspacecast doesn't compile on gfx950)
    char* Pb = SMEM + 131072;        // 16KB (2KB per wave)
    const int t = threadIdx.x;
    const int lane = t & 63;
    const int w = t >> 6;            // 0..7

    const int b = blockIdx.x;
    const int c = b & ((1 << ncs) - 1);
    const int rest = b >> ncs;
    const int qtr = rest & 31;
    const int qt = 31 - qtr;                  // heavy q-tiles first
    const int n = rest >> 5;
    const int jtop = (qt << 1) + 1;           // last kv64 tile for this q128-tile
    const int jlo = c << chs;
    if (jlo > jtop) return;
    const int jhi = (jtop < jlo + (1 << chs) - 1) ? jtop : (jlo + (1 << chs) - 1);
    const int s0 = qt << 7;
    const int wr_direct = direct || ((jtop >> chs) == 0);

    // async stage K[64][256] bf16, 16B slots XOR (row&7); linear LDS dest, pre-swizzled source
    auto stageK = [&](int j, int pb) {
        char* Kb = SMEM + (pb << 15);
        const int t0 = j << 6;
        #pragma unroll
        for (int i = 0; i < 4; ++i) {
            int rl = (i << 4) + (w << 1) + (lane >> 5);
            const short* src = (const short*)kg + ((long)(n * SS + t0 + rl)) * EE
                               + (((lane & 31) << 3) ^ ((rl & 7) << 3));
            GLOAD_LDS16(src, Kb + ((i << 4) + (w << 1)) * 512);
        }
    };
    // async stage V^T[256][64] bf16 from vo[n][o][s], 16B slots XOR (o&7)
    auto stageV = [&](int j, int pb) {
        char* Vt = SMEM + 65536 + (pb << 15);
        const int t0 = j << 6;
        #pragma unroll
        for (int i = 0; i < 4; ++i) {
            int o = (i << 6) + (w << 3) + (lane >> 3);
            const short* src = (const short*)vg + ((long)((n << 8) + o)) * SS + t0
                               + (((lane & 7) << 3) ^ ((o & 7) << 3));
            GLOAD_LDS16(src, Vt + ((i << 6) + (w << 3)) * 128);
        }
    };

    // Q fragments in registers (16 q-rows per wave)
    bf16x8 qf[8];
    {
        int qrow = s0 + (w << 4) + (lane & 15);
        const short* qp = (const short*)qg + ((long)(n * SS + qrow)) * EE;
        #pragma unroll
        for (int kf = 0; kf < 8; ++kf)
            qf[kf] = *(const bf16x8*)(qp + ((lane >> 4) << 3) + (kf << 5));
    }

    float m_[4], ls[4];
    #pragma unroll
    for (int rr = 0; rr < 4; ++rr) { m_[rr] = -3e38f; ls[rr] = 0.f; }
    f32x4 acc[16];
    #pragma unroll
    for (int ocb = 0; ocb < 16; ++ocb) acc[ocb] = (f32x4){0.f, 0.f, 0.f, 0.f};

    stageK(jlo, jlo & 1);
    stageV(jlo, jlo & 1);

    for (int j = jlo; j <= jhi; ++j) {
        const int p = j & 1;
        const int t0 = j << 6;
        char* Kb = SMEM + (p << 15);
        char* Vt = SMEM + 65536 + (p << 15);
        __syncthreads();   // vmcnt(0)+barrier: stage(j) resident; buf[p^1] free (compute j-1 done by all)

        if (j < jhi) {     // issue next-tile stage NOW; full tile of compute covers the fetch
            stageK(j + 1, p ^ 1);
            stageV(j + 1, p ^ 1);
        }

        // ---- S = Q K^T (16 q x 64 k per wave)
        f32x4 sacc[4];
        #pragma unroll
        for (int cb = 0; cb < 4; ++cb) sacc[cb] = (f32x4){0.f, 0.f, 0.f, 0.f};
        #pragma unroll
        for (int cb = 0; cb < 4; ++cb) {
            int row = (cb << 4) + (lane & 15);
            #pragma unroll
            for (int kf = 0; kf < 8; ++kf) {
                int slot = (lane >> 4) + (kf << 2);
                bf16x8 kb = *(const bf16x8*)(Kb + row * 512 + ((slot ^ (row & 7)) << 4));
                sacc[cb] = __builtin_amdgcn_mfma_f32_16x16x32_bf16(qf[kf], kb, sacc[cb], 0, 0, 0);
            }
        }

        if ((j >> 1) == qt) {   // causal mask (diagonal spans kv64 tiles 2qt, 2qt+1)
            #pragma unroll
            for (int cb = 0; cb < 4; ++cb) {
                int key = t0 + (cb << 4) + (lane & 15);
                #pragma unroll
                for (int rr = 0; rr < 4; ++rr) {
                    int qr = s0 + (w << 4) + ((lane >> 4) << 2) + rr;
                    if (key > qr) sacc[cb][rr] = -1e30f;
                }
            }
        }

        // ---- online softmax, 4 rows' reduction chains interleaved
        float mx[4], ps[4], scl[4];
        #pragma unroll
        for (int rr = 0; rr < 4; ++rr)
            mx[rr] = fmaxf(fmaxf(sacc[0][rr], sacc[1][rr]), fmaxf(sacc[2][rr], sacc[3][rr]));
        #pragma unroll
        for (int off = 1; off < 16; off <<= 1) {
            #pragma unroll
            for (int rr = 0; rr < 4; ++rr) mx[rr] = fmaxf(mx[rr], __shfl_xor(mx[rr], off));
        }
        float pv[4][4];
        #pragma unroll
        for (int rr = 0; rr < 4; ++rr) {
            float mn = fmaxf(m_[rr], mx[rr]);
            scl[rr] = exp2f(m_[rr] - mn);
            m_[rr] = mn;
        }
        #pragma unroll
        for (int cb = 0; cb < 4; ++cb)
            #pragma unroll
            for (int rr = 0; rr < 4; ++rr) pv[cb][rr] = exp2f(sacc[cb][rr] - m_[rr]);
        #pragma unroll
        for (int rr = 0; rr < 4; ++rr)
            ps[rr] = (pv[0][rr] + pv[1][rr]) + (pv[2][rr] + pv[3][rr]);
        #pragma unroll
        for (int off = 1; off < 16; off <<= 1) {
            #pragma unroll
            for (int rr = 0; rr < 4; ++rr) ps[rr] += __shfl_xor(ps[rr], off);
        }
        #pragma unroll
        for (int rr = 0; rr < 4; ++rr) ls[rr] = ls[rr] * scl[rr] + ps[rr];

        // ---- P -> per-wave LDS (16 rows x 128B, 16B-slot XOR (row&7))
        #pragma unroll
        for (int cb = 0; cb < 4; ++cb)
            #pragma unroll
            for (int rr = 0; rr < 4; ++rr) {
                int row = ((lane >> 4) << 2) + rr;
                int col = (cb << 4) + (lane & 15);
                *(__bf16*)(Pb + (w << 11) + (row << 7)
                           + (((col >> 3) ^ (row & 7)) << 4) + ((col & 7) << 1)) = (__bf16)pv[cb][rr];
            }

        #pragma unroll
        for (int ocb = 0; ocb < 16; ++ocb)
            #pragma unroll
            for (int rr = 0; rr < 4; ++rr) acc[ocb][rr] *= scl[rr];

        // ---- PV: P (own-wave LDS) x V^T (LDS)
        bf16x8 pa[2];
        #pragma unroll
        for (int kf2 = 0; kf2 < 2; ++kf2) {
            int prow = lane & 15;
            int pslot = (lane >> 4) + (kf2 << 2);
            pa[kf2] = *(const bf16x8*)(Pb + (w << 11) + (prow << 7) + ((pslot ^ (prow & 7)) << 4));
        }
        #pragma unroll
        for (int ocb = 0; ocb < 16; ++ocb) {
            int orow = (ocb << 4) + (lane & 15);
            #pragma unroll
            for (int kf2 = 0; kf2 < 2; ++kf2) {
                int slot = (lane >> 4) + (kf2 << 2);
                bf16x8 vb = *(const bf16x8*)(Vt + (orow << 7) + ((slot ^ (orow & 7)) << 4));
                acc[ocb] = __builtin_amdgcn_mfma_f32_16x16x32_bf16(pa[kf2], vb, acc[ocb], 0, 0, 0);
            }
        }
    }

    // ---- per-row stats (partial mode only)
    if (!wr_direct && (lane & 15) == 0) {
        #pragma unroll
        for (int rr = 0; rr < 4; ++rr) {
            int s = (w << 4) + ((lane >> 4) << 2) + rr;
            pstats[(long)b * 128 + s] = make_float2(m_[rr], ls[rr]);
        }
    }

    // ---- epilogue: 8 stages of 32 o-rows; transpose via LDS T[32][132] f32 (reuse SMEM)
    float inv[4];
    #pragma unroll
    for (int rr = 0; rr < 4; ++rr) inv[rr] = wr_direct ? (1.0f / ls[rr]) : 1.0f;
    float* T = (float*)SMEM;  // 32*132*4 = 16.9KB

#define EPI_STAGE(g)                                                                    \
    do {                                                                                \
        __syncthreads();                                                                \
        _Pragma("unroll")                                                               \
        for (int e = 0; e < 2; ++e) {                                                   \
            _Pragma("unroll")                                                           \
            for (int rr = 0; rr < 4; ++rr) {                                            \
                int ol = (e << 4) + (lane & 15);                                        \
                int cl = (w << 4) + ((lane >> 4) << 2) + rr;                            \
                T[ol * 132 + cl] = acc[((g) << 1) + e][rr] * inv[rr];                   \
            }                                                                           \
        }                                                                               \
        __syncthreads();                                                                \
        {                                                                               \
            int row = t >> 4;                  /* 0..31 */                              \
            int c0 = (t & 15) << 3;            /* 8 f32 per thread */                   \
            float* dp = wr_direct                                                       \
                ? (out + ((long)((n << 8) + ((g) << 5) + row)) * SS + s0 + c0)          \
                : (pacc + ((long)b << 15) + ((((g) << 5) + row) << 7) + c0);            \
            f32x4 r0 = *(const f32x4*)(T + row * 132 + c0);                             \
            f32x4 r1 = *(const f32x4*)(T + row * 132 + c0 + 4);                         \
            *(f32x4*)dp = r0;                                                           \
            *(f32x4*)(dp + 4) = r1;                                                     \
        }                                                                               \
    } while (0)

    EPI_STAGE(0); EPI_STAGE(1); EPI_STAGE(2); EPI_STAGE(3);
    EPI_STAGE(4); EPI_STAGE(5); EPI_STAGE(6); EPI_STAGE(7);
#undef EPI_STAGE
}

// ---------------- combine partials (skip single-chunk q-tiles: written direct) ----------------
__global__ __launch_bounds__(256) void combine_kernel(const float* __restrict__ pacc,
                                                      const float2* __restrict__ pstats,
                                                      float* __restrict__ out,
                                                      int chs, int ncs) {
    const int t = threadIdx.x;
    const int b2 = blockIdx.x;
    const int og = b2 & 7;               // 32-o slice
    const int qtr = (b2 >> 3) & 31;
    const int qt = 31 - qtr;
    const int n = b2 >> 8;
    const int jtop = (qt << 1) + 1;
    const int nch = (jtop >> chs) + 1;
    if (nch == 1) return;
    const long sb0 = (long)(((n << 5) + qtr) << ncs);

    __shared__ float wsc[8][128];
    __shared__ float invL[128];
    if (t < 128) {
        float M = -3e38f;
        for (int c2 = 0; c2 < nch; ++c2) M = fmaxf(M, pstats[(sb0 + c2) * 128 + t].x);
        float L = 0.f;
        for (int c2 = 0; c2 < nch; ++c2) {
            float2 st = pstats[(sb0 + c2) * 128 + t];
            float wv = exp2f(st.x - M);
            wsc[c2][t] = wv;
            L += st.y * wv;
        }
        invL[t] = 1.f / L;
    }
    __syncthreads();

    const int o = (og << 5) + (t >> 3);  // 32 o-rows
    const int sc = (t & 7) << 4;         // 16 f32 per thread
    float a[16];
    #pragma unroll
    for (int i = 0; i < 16; ++i) a[i] = 0.f;
    for (int c2 = 0; c2 < nch; ++c2) {
        const float* p = pacc + ((sb0 + c2) << 15) + (o << 7) + sc;
        #pragma unroll
        for (int u = 0; u < 4; ++u) {
            f32x4 v = *(const f32x4*)(p + (u << 2));
            #pragma unroll
            for (int k2 = 0; k2 < 4; ++k2) a[(u << 2) + k2] += v[k2] * wsc[c2][sc + (u << 2) + k2];
        }
    }
    float* op = out + ((long)((n << 8) + o)) * SS + (qt << 7) + sc;
    #pragma unroll
    for (int u = 0; u < 4; ++u) {
        f32x4 r;
        #pragma unroll
        for (int k2 = 0; k2 < 4; ++k2) r[k2] = a[(u << 2) + k2] * invL[sc + (u << 2) + k2];
        *(f32x4*)(op + (u << 2)) = r;
    }
}

extern "C" void kernel_launch(void* const* d_in, const int* in_sizes, int n_in,
                              void* d_out, int out_size, void* d_ws, size_t ws_size,
                              hipStream_t stream) {
    const float* x   = (const float*)d_in[0];
    const float* Wq  = (const float*)d_in[1];
    const float* bq  = (const float*)d_in[2];
    const float* Wkv = (const float*)d_in[3];
    const float* bkv = (const float*)d_in[4];
    float* out = (float*)d_out;
    char* ws = (char*)d_ws;
    __bf16* qw = (__bf16*)(ws + QOFF);
    __bf16* kw = (__bf16*)(ws + KOFF);
    __bf16* vw = (__bf16*)(ws + VOFF);
    __bf16* wc = (__bf16*)(ws + WOFF);
    float*  bias = (float*)(ws + BOFF);

    // split-KV: 1024 slots x (256o x 128s f32) partials + stats
    size_t need = (size_t)PAOFF + (size_t)1024 * 131072 + (size_t)1024 * 1024;
    int direct = (ws_size < need) ? 1 : 0;
    int ncs = direct ? 0 : 3;     // chunks per q128-tile (log2)
    int chs = direct ? 6 : 3;     // kv64 tiles per chunk (log2)
    float* pacc = (float*)(ws + PAOFF);
    float2* pstats = (float2*)(ws + PAOFF + (size_t)1024 * 131072);

    prep_kernel<<<dim3(768), dim3(256), 0, stream>>>(Wq, bq, Wkv, bkv, wc, bias);
    proj_kernel<<<dim3(256), dim3(256), 0, stream>>>(x, wc, bias, qw, kw, vw);
    attn_kernel<<<dim3(128 << ncs), dim3(512), 0, stream>>>(qw, kw, vw, out, pacc, pstats,
                                                            chs, ncs, direct);
    if (!direct)
        combine_kernel<<<dim3(1024), dim3(256), 0, stream>>>(pacc, pstats, out, chs, ncs);
}

// Round 13
// 194.620 us; speedup vs baseline: 1.9457x; 1.0232x over previous
//
#include <hip/hip_runtime.h>
#include <hip/hip_bf16.h>

typedef __bf16 bf16x8 __attribute__((ext_vector_type(8)));
typedef float f32x4 __attribute__((ext_vector_type(4)));
typedef short short8 __attribute__((ext_vector_type(8)));
typedef short short4v __attribute__((ext_vector_type(4)));

#define NB 4
#define CC 256
#define SS 4096
#define EE 256

static constexpr float QSCALE = 1.4426950408889634f / 16.0f;  // log2(e)/sqrt(E)

// workspace offsets (bytes)
#define QOFF 0u
#define KOFF 8388608u
#define VOFF 16777216u
#define WOFF 25165824u
#define BOFF 25559040u
#define PAOFF 25690112u   // partial acc f32 [slot][256 o][128 s], then stats float2 [slot][128 s]

#define GLOAD_LDS16(gsrc, ldst) \
    __builtin_amdgcn_global_load_lds((const __attribute__((address_space(1))) void*)(gsrc), \
                                     (__attribute__((address_space(3))) void*)(ldst), 16, 0, 0)

// ---------------- weight prep: fp32 -> bf16 (q rows pre-scaled) ----------------
__global__ __launch_bounds__(256) void prep_kernel(const float* __restrict__ Wq,
                                                   const float* __restrict__ bq,
                                                   const float* __restrict__ Wkv,
                                                   const float* __restrict__ bkv,
                                                   __bf16* __restrict__ wc,
                                                   float* __restrict__ bias) {
    int r = blockIdx.x;
    int t = threadIdx.x;
    float v;
    if (r < 256) v = Wq[r * 256 + t] * QSCALE;
    else         v = Wkv[(r - 256) * 256 + t];
    wc[r * 256 + t] = (__bf16)v;
    if (t == 0) bias[r] = (r < 256) ? bq[r] * QSCALE : bkv[r - 256];
}

// ---------------- projection: q,k [n][S][E] bf16 ; v transposed [n][O][S] bf16 ----------------
__global__ __launch_bounds__(256) void proj_kernel(const float* __restrict__ x,
                                                   const __bf16* __restrict__ wc,
                                                   const float* __restrict__ bias,
                                                   __bf16* __restrict__ qo,
                                                   __bf16* __restrict__ ko,
                                                   __bf16* __restrict__ vo) {
    __shared__ __align__(16) char Ab[32768];
    __shared__ __align__(16) char Wb[32768];
    const int t = threadIdx.x;
    const int lane = t & 63;
    const int w = t >> 6;
    const int n = blockIdx.x >> 6;
    const int s0 = (blockIdx.x & 63) << 6;

    {
        const int sl = t & 15;
        const int cc0 = t >> 4;
        #pragma unroll
        for (int it = 0; it < 2; ++it) {
            int c0 = (cc0 + (it << 4)) << 3;
            float f[8][4];
            #pragma unroll
            for (int r = 0; r < 8; ++r) {
                const float* xp = x + ((long)(n * CC + c0 + r)) * SS + s0 + sl;
                #pragma unroll
                for (int i = 0; i < 4; ++i) f[r][i] = xp[i << 4];
            }
            #pragma unroll
            for (int i = 0; i < 4; ++i) {
                bf16x8 v;
                #pragma unroll
                for (int r = 0; r < 8; ++r) v[r] = (__bf16)f[r][i];
                int srow = sl + (i << 4);
                *(bf16x8*)(Ab + srow * 512 + ((c0 * 2) ^ ((srow & 7) << 4))) = v;
            }
        }
    }
    __syncthreads();

    bf16x8 af[8];
    {
        int arow = (w << 4) + (lane & 15);
        #pragma unroll
        for (int kf = 0; kf < 8; ++kf) {
            int c = ((lane >> 4) << 3) + (kf << 5);
            af[kf] = *(const bf16x8*)(Ab + arow * 512 + ((c * 2) ^ ((arow & 7) << 4)));
        }
    }

    for (int ot = 0; ot < 12; ++ot) {
        #pragma unroll
        for (int p = 0; p < 16; ++p) {
            int row = w + (p << 2);
            int c = lane << 2;
            short4v vv = *(const short4v*)((const short*)wc + (ot * 64 + row) * 256 + c);
            *(short4v*)(Wb + row * 512 + ((c * 2) ^ ((row & 7) << 4))) = vv;
        }
        __syncthreads();

        f32x4 acc[4];
        #pragma unroll
        for (int cb = 0; cb < 4; ++cb) acc[cb] = (f32x4){0.f, 0.f, 0.f, 0.f};
        #pragma unroll
        for (int cb = 0; cb < 4; ++cb) {
            int row = (cb << 4) + (lane & 15);
            #pragma unroll
            for (int kf = 0; kf < 8; ++kf) {
                int c = ((lane >> 4) << 3) + (kf << 5);
                bf16x8 bfr = *(const bf16x8*)(Wb + row * 512 + ((c * 2) ^ ((row & 7) << 4)));
                acc[cb] = __builtin_amdgcn_mfma_f32_16x16x32_bf16(af[kf], bfr, acc[cb], 0, 0, 0);
            }
        }
        __syncthreads();

        __bf16* T = (__bf16*)Wb;
        float bsv[4];
        #pragma unroll
        for (int cb = 0; cb < 4; ++cb) bsv[cb] = bias[ot * 64 + (cb << 4) + (lane & 15)];

        if (ot < 8) {
            #pragma unroll
            for (int cb = 0; cb < 4; ++cb) {
                #pragma unroll
                for (int jj = 0; jj < 4; ++jj) {
                    int srow = (w << 4) + ((lane >> 4) << 2) + jj;
                    T[srow * 72 + (cb << 4) + (lane & 15)] = (__bf16)(acc[cb][jj] + bsv[cb]);
                }
            }
            __syncthreads();
            int s = t >> 2;
            int o0 = (t & 3) << 4;
            short8 r0 = *(const short8*)((const short*)T + s * 72 + o0);
            short8 r1 = *(const short8*)((const short*)T + s * 72 + o0 + 8);
            __bf16* dst = (ot < 4) ? qo : ko;
            long idx = ((long)(n * SS + s0 + s)) * EE + ((ot & 3) << 6) + o0;
            *(short8*)((short*)dst + idx) = r0;
            *(short8*)((short*)dst + idx + 8) = r1;
        } else {
            #pragma unroll
            for (int cb = 0; cb < 4; ++cb) {
                #pragma unroll
                for (int jj = 0; jj < 4; ++jj) {
                    int srow = (w << 4) + ((lane >> 4) << 2) + jj;
                    T[((cb << 4) + (lane & 15)) * 72 + srow] = (__bf16)(acc[cb][jj] + bsv[cb]);
                }
            }
            __syncthreads();
            int o = t >> 2;
            int sc0 = (t & 3) << 4;
            short8 r0 = *(const short8*)((const short*)T + o * 72 + sc0);
            short8 r1 = *(const short8*)((const short*)T + o * 72 + sc0 + 8);
            long idx = ((long)((n << 8) + ((ot - 8) << 6) + o)) * SS + s0 + sc0;
            *(short8*)((short*)vo + idx) = r0;
            *(short8*)((short*)vo + idx + 8) = r1;
        }
        __syncthreads();
    }
}

// ---------------- causal flash attention: QBLK=128 (8 waves), KVBLK=64, dbuf K+V, 1 barrier/tile ----------------
// R10-verified compute path. New: (1) batch->XCD-pair affinity decode; (2) defer-max (T13, THR=8 log2).
// LDS (144KB, 1 block/CU): K[2][64][256] 64KB | V^T[2][256][64] 64KB | P[8][16][64] swz 16KB
__global__ __launch_bounds__(512, 2) void attn_kernel(const __bf16* __restrict__ qg,
                                                      const __bf16* __restrict__ kg,
                                                      const __bf16* __restrict__ vg,
                                                      float* __restrict__ out,
                                                      float* __restrict__ pacc,
                                                      float2* __restrict__ pstats,
                                                      int chs, int ncs, int direct) {
    __shared__ __align__(16) char SMEM[147456];
    char* Pb = SMEM + 131072;        // 16KB (2KB per wave)
    const int t = threadIdx.x;
    const int lane = t & 63;
    const int w = t >> 6;            // 0..7

    // batch->XCD-pair affinity: xcd = b&7, batch n = xcd>>1; id enumerates within-batch work.
    // slot = (n<<(5+ncs)) + id == ((n<<5)+qtr)<<ncs) + c  -> matches combine's sb0 arithmetic.
    const int xcd = blockIdx.x & 7;
    const int n = xcd >> 1;
    const int id = ((blockIdx.x >> 3) << 1) | (xcd & 1);
    const int c = id & ((1 << ncs) - 1);
    const int qtr = (id >> ncs) & 31;
    const int qt = 31 - qtr;                  // heavy q-tiles first
    const long slot = ((long)n << (5 + ncs)) + id;
    const int jtop = (qt << 1) + 1;           // last kv64 tile for this q128-tile
    const int jlo = c << chs;
    if (jlo > jtop) return;
    const int jhi = (jtop < jlo + (1 << chs) - 1) ? jtop : (jlo + (1 << chs) - 1);
    const int s0 = qt << 7;
    const int wr_direct = direct || ((jtop >> chs) == 0);

    // async stage K[64][256] bf16, 16B slots XOR (row&7); linear LDS dest, pre-swizzled source
    auto stageK = [&](int j, int pb) {
        char* Kb = SMEM + (pb << 15);
        const int t0 = j << 6;
        #pragma unroll
        for (int i = 0; i < 4; ++i) {
            int rl = (i << 4) + (w << 1) + (lane >> 5);
            const short* src = (const short*)kg + ((long)(n * SS + t0 + rl)) * EE
                               + (((lane & 31) << 3) ^ ((rl & 7) << 3));
            GLOAD_LDS16(src, Kb + ((i << 4) + (w << 1)) * 512);
        }
    };
    // async stage V^T[256][64] bf16 from vo[n][o][s], 16B slots XOR (o&7)
    auto stageV = [&](int j, int pb) {
        char* Vt = SMEM + 65536 + (pb << 15);
        const int t0 = j << 6;
        #pragma unroll
        for (int i = 0; i < 4; ++i) {
            int o = (i << 6) + (w << 3) + (lane >> 3);
            const short* src = (const short*)vg + ((long)((n << 8) + o)) * SS + t0
                               + (((lane & 7) << 3) ^ ((o & 7) << 3));
            GLOAD_LDS16(src, Vt + ((i << 6) + (w << 3)) * 128);
        }
    };

    // Q fragments in registers (16 q-rows per wave)
    bf16x8 qf[8];
    {
        int qrow = s0 + (w << 4) + (lane & 15);
        const short* qp = (const short*)qg + ((long)(n * SS + qrow)) * EE;
        #pragma unroll
        for (int kf = 0; kf < 8; ++kf)
            qf[kf] = *(const bf16x8*)(qp + ((lane >> 4) << 3) + (kf << 5));
    }

    float m_[4], ls[4];
    #pragma unroll
    for (int rr = 0; rr < 4; ++rr) { m_[rr] = -3e38f; ls[rr] = 0.f; }
    f32x4 acc[16];
    #pragma unroll
    for (int ocb = 0; ocb < 16; ++ocb) acc[ocb] = (f32x4){0.f, 0.f, 0.f, 0.f};

    stageK(jlo, jlo & 1);
    stageV(jlo, jlo & 1);

    for (int j = jlo; j <= jhi; ++j) {
        const int p = j & 1;
        const int t0 = j << 6;
        char* Kb = SMEM + (p << 15);
        char* Vt = SMEM + 65536 + (p << 15);
        __syncthreads();   // vmcnt(0)+barrier: stage(j) resident; buf[p^1] free (compute j-1 done by all)

        if (j < jhi) {     // issue next-tile stage NOW; full tile of compute covers the fetch
            stageK(j + 1, p ^ 1);
            stageV(j + 1, p ^ 1);
        }

        // ---- S = Q K^T (16 q x 64 k per wave)
        f32x4 sacc[4];
        #pragma unroll
        for (int cb = 0; cb < 4; ++cb) sacc[cb] = (f32x4){0.f, 0.f, 0.f, 0.f};
        #pragma unroll
        for (int cb = 0; cb < 4; ++cb) {
            int row = (cb << 4) + (lane & 15);
            #pragma unroll
            for (int kf = 0; kf < 8; ++kf) {
                int slotk = (lane >> 4) + (kf << 2);
                bf16x8 kb = *(const bf16x8*)(Kb + row * 512 + ((slotk ^ (row & 7)) << 4));
                sacc[cb] = __builtin_amdgcn_mfma_f32_16x16x32_bf16(qf[kf], kb, sacc[cb], 0, 0, 0);
            }
        }

        if ((j >> 1) == qt) {   // causal mask (diagonal spans kv64 tiles 2qt, 2qt+1)
            #pragma unroll
            for (int cb = 0; cb < 4; ++cb) {
                int key = t0 + (cb << 4) + (lane & 15);
                #pragma unroll
                for (int rr = 0; rr < 4; ++rr) {
                    int qr = s0 + (w << 4) + ((lane >> 4) << 2) + rr;
                    if (key > qr) sacc[cb][rr] = -1e30f;
                }
            }
        }

        // ---- online softmax, 4 rows' reduction chains interleaved; defer-max (T13)
        float mx[4], ps[4], scl[4];
        #pragma unroll
        for (int rr = 0; rr < 4; ++rr)
            mx[rr] = fmaxf(fmaxf(sacc[0][rr], sacc[1][rr]), fmaxf(sacc[2][rr], sacc[3][rr]));
        #pragma unroll
        for (int off = 1; off < 16; off <<= 1) {
            #pragma unroll
            for (int rr = 0; rr < 4; ++rr) mx[rr] = fmaxf(mx[rr], __shfl_xor(mx[rr], off));
        }
        bool okd = true;
        #pragma unroll
        for (int rr = 0; rr < 4; ++rr) okd = okd && (mx[rr] - m_[rr] <= 8.0f);
        const bool need_rescale = !__all(okd);
        if (need_rescale) {
            #pragma unroll
            for (int rr = 0; rr < 4; ++rr) {
                float mn = fmaxf(m_[rr], mx[rr]);
                scl[rr] = exp2f(m_[rr] - mn);
                m_[rr] = mn;
            }
        } else {
            #pragma unroll
            for (int rr = 0; rr < 4; ++rr) scl[rr] = 1.0f;
        }
        float pv[4][4];
        #pragma unroll
        for (int cb = 0; cb < 4; ++cb)
            #pragma unroll
            for (int rr = 0; rr < 4; ++rr) pv[cb][rr] = exp2f(sacc[cb][rr] - m_[rr]);
        #pragma unroll
        for (int rr = 0; rr < 4; ++rr)
            ps[rr] = (pv[0][rr] + pv[1][rr]) + (pv[2][rr] + pv[3][rr]);
        #pragma unroll
        for (int off = 1; off < 16; off <<= 1) {
            #pragma unroll
            for (int rr = 0; rr < 4; ++rr) ps[rr] += __shfl_xor(ps[rr], off);
        }
        #pragma unroll
        for (int rr = 0; rr < 4; ++rr) ls[rr] = ls[rr] * scl[rr] + ps[rr];

        // ---- P -> per-wave LDS (16 rows x 128B, 16B-slot XOR (row&7))
        #pragma unroll
        for (int cb = 0; cb < 4; ++cb)
            #pragma unroll
            for (int rr = 0; rr < 4; ++rr) {
                int row = ((lane >> 4) << 2) + rr;
                int col = (cb << 4) + (lane & 15);
                *(__bf16*)(Pb + (w << 11) + (row << 7)
                           + (((col >> 3) ^ (row & 7)) << 4) + ((col & 7) << 1)) = (__bf16)pv[cb][rr];
            }

        if (need_rescale) {
            #pragma unroll
            for (int ocb = 0; ocb < 16; ++ocb)
                #pragma unroll
                for (int rr = 0; rr < 4; ++rr) acc[ocb][rr] *= scl[rr];
        }

        // ---- PV: P (own-wave LDS) x V^T (LDS)
        bf16x8 pa[2];
        #pragma unroll
        for (int kf2 = 0; kf2 < 2; ++kf2) {
            int prow = lane & 15;
            int pslot = (lane >> 4) + (kf2 << 2);
            pa[kf2] = *(const bf16x8*)(Pb + (w << 11) + (prow << 7) + ((pslot ^ (prow & 7)) << 4));
        }
        #pragma unroll
        for (int ocb = 0; ocb < 16; ++ocb) {
            int orow = (ocb << 4) + (lane & 15);
            #pragma unroll
            for (int kf2 = 0; kf2 < 2; ++kf2) {
                int slotv = (lane >> 4) + (kf2 << 2);
                bf16x8 vb = *(const bf16x8*)(Vt + (orow << 7) + ((slotv ^ (orow & 7)) << 4));
                acc[ocb] = __builtin_amdgcn_mfma_f32_16x16x32_bf16(pa[kf2], vb, acc[ocb], 0, 0, 0);
            }
        }
    }

    // ---- per-row stats (partial mode only)
    if (!wr_direct && (lane & 15) == 0) {
        #pragma unroll
        for (int rr = 0; rr < 4; ++rr) {
            int s = (w << 4) + ((lane >> 4) << 2) + rr;
            pstats[slot * 128 + s] = make_float2(m_[rr], ls[rr]);
        }
    }

    // ---- epilogue: 8 stages of 32 o-rows; transpose via LDS T[32][132] f32 (reuse SMEM)
    float inv[4];
    #pragma unroll
    for (int rr = 0; rr < 4; ++rr) inv[rr] = wr_direct ? (1.0f / ls[rr]) : 1.0f;
    float* T = (float*)SMEM;  // 32*132*4 = 16.9KB

#define EPI_STAGE(g)                                                                    \
    do {                                                                                \
        __syncthreads();                                                                \
        _Pragma("unroll")                                                               \
        for (int e = 0; e < 2; ++e) {                                                   \
            _Pragma("unroll")                                                           \
            for (int rr = 0; rr < 4; ++rr) {                                            \
                int ol = (e << 4) + (lane & 15);                                        \
                int cl = (w << 4) + ((lane >> 4) << 2) + rr;                            \
                T[ol * 132 + cl] = acc[((g) << 1) + e][rr] * inv[rr];                   \
            }                                                                           \
        }                                                                               \
        __syncthreads();                                                                \
        {                                                                               \
            int row = t >> 4;                  /* 0..31 */                              \
            int c0 = (t & 15) << 3;            /* 8 f32 per thread */                   \
            float* dp = wr_direct                                                       \
                ? (out + ((long)((n << 8) + ((g) << 5) + row)) * SS + s0 + c0)          \
                : (pacc + (slot << 15) + ((((g) << 5) + row) << 7) + c0);               \
            f32x4 r0 = *(const f32x4*)(T + row * 132 + c0);                             \
            f32x4 r1 = *(const f32x4*)(T + row * 132 + c0 + 4);                         \
            *(f32x4*)dp = r0;                                                           \
            *(f32x4*)(dp + 4) = r1;                                                     \
        }                                                                               \
    } while (0)

    EPI_STAGE(0); EPI_STAGE(1); EPI_STAGE(2); EPI_STAGE(3);
    EPI_STAGE(4); EPI_STAGE(5); EPI_STAGE(6); EPI_STAGE(7);
#undef EPI_STAGE
}

// ---------------- combine partials (skip single-chunk q-tiles: written direct) ----------------
__global__ __launch_bounds__(256) void combine_kernel(const float* __restrict__ pacc,
                                                      const float2* __restrict__ pstats,
                                                      float* __restrict__ out,
                                                      int chs, int ncs) {
    const int t = threadIdx.x;
    const int b2 = blockIdx.x;
    const int og = b2 & 7;               // 32-o slice
    const int qtr = (b2 >> 3) & 31;
    const int qt = 31 - qtr;
    const int n = b2 >> 8;
    const int jtop = (qt << 1) + 1;
    const int nch = (jtop >> chs) + 1;
    if (nch == 1) return;
    const long sb0 = (long)(((n << 5) + qtr) << ncs);

    __shared__ float wsc[8][128];
    __shared__ float invL[128];
    if (t < 128) {
        float M = -3e38f;
        for (int c2 = 0; c2 < nch; ++c2) M = fmaxf(M, pstats[(sb0 + c2) * 128 + t].x);
        float L = 0.f;
        for (int c2 = 0; c2 < nch; ++c2) {
            float2 st = pstats[(sb0 + c2) * 128 + t];
            float wv = exp2f(st.x - M);
            wsc[c2][t] = wv;
            L += st.y * wv;
        }
        invL[t] = 1.f / L;
    }
    __syncthreads();

    const int o = (og << 5) + (t >> 3);  // 32 o-rows
    const int sc = (t & 7) << 4;         // 16 f32 per thread
    float a[16];
    #pragma unroll
    for (int i = 0; i < 16; ++i) a[i] = 0.f;
    for (int c2 = 0; c2 < nch; ++c2) {
        const float* p = pacc + ((sb0 + c2) << 15) + (o << 7) + sc;
        #pragma unroll
        for (int u = 0; u < 4; ++u) {
            f32x4 v = *(const f32x4*)(p + (u << 2));
            #pragma unroll
            for (int k2 = 0; k2 < 4; ++k2) a[(u << 2) + k2] += v[k2] * wsc[c2][sc + (u << 2) + k2];
        }
    }
    float* op = out + ((long)((n << 8) + o)) * SS + (qt << 7) + sc;
    #pragma unroll
    for (int u = 0; u < 4; ++u) {
        f32x4 r;
        #pragma unroll
        for (int k2 = 0; k2 < 4; ++k2) r[k2] = a[(u << 2) + k2] * invL[sc + (u << 2) + k2];
        *(f32x4*)(op + (u << 2)) = r;
    }
}

extern "C" void kernel_launch(void* const* d_in, const int* in_sizes, int n_in,
                              void* d_out, int out_size, void* d_ws, size_t ws_size,
                              hipStream_t stream) {
    const float* x   = (const float*)d_in[0];
    const float* Wq  = (const float*)d_in[1];
    const float* bq  = (const float*)d_in[2];
    const float* Wkv = (const float*)d_in[3];
    const float* bkv = (const float*)d_in[4];
    float* out = (float*)d_out;
    char* ws = (char*)d_ws;
    __bf16* qw = (__bf16*)(ws + QOFF);
    __bf16* kw = (__bf16*)(ws + KOFF);
    __bf16* vw = (__bf16*)(ws + VOFF);
    __bf16* wc = (__bf16*)(ws + WOFF);
    float*  bias = (float*)(ws + BOFF);

    // split-KV: 1024 slots x (256o x 128s f32) partials + stats
    size_t need = (size_t)PAOFF + (size_t)1024 * 131072 + (size_t)1024 * 1024;
    int direct = (ws_size < need) ? 1 : 0;
    int ncs = direct ? 0 : 3;     // chunks per q128-tile (log2)
    int chs = direct ? 6 : 3;     // kv64 tiles per chunk (log2)
    float* pacc = (float*)(ws + PAOFF);
    float2* pstats = (float2*)(ws + PAOFF + (size_t)1024 * 131072);

    prep_kernel<<<dim3(768), dim3(256), 0, stream>>>(Wq, bq, Wkv, bkv, wc, bias);
    proj_kernel<<<dim3(256), dim3(256), 0, stream>>>(x, wc, bias, qw, kw, vw);
    attn_kernel<<<dim3(128 << ncs), dim3(512), 0, stream>>>(qw, kw, vw, out, pacc, pstats,
                                                            chs, ncs, direct);
    if (!direct)
        combine_kernel<<<dim3(1024), dim3(256), 0, stream>>>(pacc, pstats, out, chs, ncs);
}